// Round 10
// baseline (391.593 us; speedup 1.0000x reference)
//
#include <hip/hip_runtime.h>

// ContextAttentionBlock fused kernel for gfx950.
// Per (b,h) row-strip (2048 strips of [128x128]): everything in LDS with
// bf16 MFMA (32x32x16), fp32 accum. Shortcut conv folded into the output
// projection (w_sc @ Wo1 precomputed).
//
// R10 structure: 512 thr / 8 waves; each wave owns TWO 32x32 tiles in the
// same row-band (rows rt*32.., cols cp*64 and cp*64+32):
//  - A-fragments shared across the 2 tiles in every GEMM phase.
//  - XB A-fragments cached in registers (xf[8], 32 VGPR) for the whole strip
//    -> B1/B2/B3/E3 have ZERO LDS reads. LDS b128 reads: 1280 -> 512/strip/CU.
//  - barriers are lgkmcnt-only (s_barrier), so the x-prefetch global loads
//    stay in flight across barriers (__syncthreads drains vmcnt(0)).
//  - xf-indexed loops fully unrolled (static idx) + sched_barrier(0) every
//    2 MFMAs to cap load hoisting (R5 spill mechanism).
// Measured history: R6 unroll2 fix 370->242; R8 16-wave TLP 242->162; R9
// native-cvt neutral. VGPR cap = 65536/blockDim (512->128).

typedef __bf16 bf16x8 __attribute__((ext_vector_type(8)));
typedef __bf16 bf16x4 __attribute__((ext_vector_type(4)));
typedef float f32x16 __attribute__((ext_vector_type(16)));

__device__ __forceinline__ int swz(int row, int cb) {
    return (row << 8) + (cb ^ ((row & 15) << 4));
}
__device__ __forceinline__ float sigm(float t) {
    return 1.0f / (1.0f + __expf(-t));
}
// lgkm-only barrier: LDS writes visible to the block, but vmcnt (global
// prefetch loads) NOT drained.
__device__ __forceinline__ void bar() {
    asm volatile("s_waitcnt lgkmcnt(0)" ::: "memory");
    __builtin_amdgcn_s_barrier();
    asm volatile("" ::: "memory");
}

// ---------------- pre-pass 1: combined shortcut weight -----------------
__global__ void prep_combine(const float* __restrict__ w_sc,
                             const float* __restrict__ b_sc,
                             const float* __restrict__ w_out,
                             const float* __restrict__ b_out,
                             float* __restrict__ wsc2,
                             float* __restrict__ bout2) {
    int k = blockIdx.x;      // 0..127
    int n = threadIdx.x;     // 0..127
    float acc = 0.f;
    for (int c = 0; c < 128; ++c)
        acc += w_sc[k * 128 + c] * w_out[(128 + c) * 128 + n];
    wsc2[k * 128 + n] = acc;
    if (k == 0) {
        float b = b_out[n];
        for (int c = 0; c < 128; ++c)
            b += b_sc[c] * w_out[(128 + c) * 128 + n];
        bout2[n] = b;
    }
}

// ---------------- pre-pass 2: pack weights into MFMA B-frag order ------
__global__ void prep_pack(const float* __restrict__ wth,
                          const float* __restrict__ wph,
                          const float* __restrict__ wg,
                          const float* __restrict__ wout,
                          const float* __restrict__ wsc2,
                          __bf16* __restrict__ packs) {
    int m = blockIdx.x;
    const float* src;
    int rowoff = 0;
    if (m == 0) src = wth;
    else if (m == 1) src = wph;
    else if (m == 2) src = wg;
    else if (m == 3) { src = wout; rowoff = 0; }
    else if (m == 4) { src = wout; rowoff = 256; }
    else src = wsc2;
    __bf16* dst = packs + m * 16384;
    for (int i = threadIdx.x; i < 16384; i += blockDim.x) {
        int j = i & 7;
        int lane = (i >> 3) & 63;
        int kk = (i >> 9) & 7;
        int nt = i >> 12;
        int k = kk * 16 + ((lane >> 5) << 3) + j;
        int n = nt * 32 + (lane & 31);
        dst[i] = (__bf16)(src[(rowoff + k) * 128 + n]);
    }
}

// ---------------- main fused kernel ------------------------------------
#define FPB 32768
#define FGT 98304

__global__ __launch_bounds__(512, 2)
void cab_main(const float* __restrict__ x,
              const float* __restrict__ b_theta,
              const float* __restrict__ b_phi,
              const float* __restrict__ b_g,
              const __bf16* __restrict__ packs,
              const float* __restrict__ bout2,
              float* __restrict__ out,
              int nstrips, int spb) {
    __shared__ __align__(16) char lds[131072];

    const int tid = threadIdx.x;
    const int l   = tid & 63;
    const int wv  = tid >> 6;          // 0..7
    const int rt  = wv >> 1;           // row tile (0..3)
    const int cp  = wv & 1;            // col pair (0..1)
    const int ln  = l & 31;
    const int lh  = l >> 5;
    const int m0    = rt * 32;         // wave's output row base
    const int colg0 = cp * 64 + ln;    // tile-0 output column
    const int colg1 = colg0 + 32;      // tile-1 output column
    const int c0    = cp * 2;          // tile-0 col-tile index
    const int c1    = c0 + 1;

    const __bf16* pTH = packs;
    const __bf16* pPH = packs + 16384;
    const __bf16* pG  = packs + 2 * 16384;
    const __bf16* pO0 = packs + 3 * 16384;
    const __bf16* pO2 = packs + 4 * 16384;
    const __bf16* pS2 = packs + 5 * 16384;

    const float biasTH0 = b_theta[colg0], biasTH1 = b_theta[colg1];
    const float biasPH0 = b_phi[colg0],   biasPH1 = b_phi[colg1];
    const float biasG0  = b_g[colg0],     biasG1  = b_g[colg1];
    const float biasO0  = bout2[colg0],   biasO1  = bout2[colg1];

    const int s0 = blockIdx.x * spb;
    if (s0 >= nstrips) return;
    const float4* x4 = (const float4*)x;

    // staging geometry (512 thr): idx = q*512+tid -> row = q*16 + (tid>>5),
    // byte col = (tid&31)*8. Chunk c covers q = c*4..c*4+3 (rows c*64..+63).
    const int srow = tid >> 5;          // 0..15
    const int scb  = (tid & 31) * 8;    // byte col

    float4 pf[4];

    // initial full stage of strip s0 into region 0
    {
        long base = (long)s0 * 4096;
#pragma unroll
        for (int c = 0; c < 2; ++c) {
#pragma unroll
            for (int q = 0; q < 4; ++q) pf[q] = x4[base + (c * 4 + q) * 512 + tid];
#pragma unroll
            for (int q = 0; q < 4; ++q) {
                int row = c * 64 + q * 16 + srow;
                bf16x4 v;
                v[0] = (__bf16)pf[q].x; v[1] = (__bf16)pf[q].y;
                v[2] = (__bf16)pf[q].z; v[3] = (__bf16)pf[q].w;
                *(bf16x4*)(lds + swz(row, scb)) = v;
            }
        }
    }
    bar();

    for (int it = 0; it < spb; ++it) {
        const int s = s0 + it;
        // rotating roles: XB holds current x; FPT region doubles as next-XB
        const int XBo  = (it & 1) ? 65536 : 0;
        const int FPTo = 65536 - XBo;
        f32x16 accA, accB;

        // cache this wave's XB A-fragments for the whole strip (32 VGPR)
        bf16x8 xf[8];
#pragma unroll
        for (int kk = 0; kk < 8; ++kk)
            xf[kk] = *(const bf16x8*)(lds + XBo + swz(m0 + ln, kk * 32 + lh * 16));

        // ===== B1: f_phi = xb @ w_phi + b  -> FPB (row-major) + FPT ([c][w])
#pragma unroll
        for (int i = 0; i < 16; ++i) { accA[i] = 0.f; accB[i] = 0.f; }
#pragma unroll
        for (int j = 0; j < 8; ++j) {
            bf16x8 b0 = *(const bf16x8*)(pPH + (((c0 * 8 + j) * 64 + l) << 3));
            bf16x8 b1 = *(const bf16x8*)(pPH + (((c1 * 8 + j) * 64 + l) << 3));
            accA = __builtin_amdgcn_mfma_f32_32x32x16_bf16(xf[j], b0, accA, 0, 0, 0);
            accB = __builtin_amdgcn_mfma_f32_32x32x16_bf16(xf[j], b1, accB, 0, 0, 0);
            if (j & 1) __builtin_amdgcn_sched_barrier(0);
        }
#pragma unroll
        for (int t = 0; t < 2; ++t) {
            const f32x16& acc = t ? accB : accA;
            int cg = colg0 + t * 32;
            float bias = t ? biasPH1 : biasPH0;
#pragma unroll
            for (int r = 0; r < 16; ++r) {
                int row = m0 + (r & 3) + ((r >> 2) << 3) + (lh << 2);
                *(__bf16*)(lds + FPB + swz(row, cg * 2)) = (__bf16)(acc[r] + bias);
            }
#pragma unroll
            for (int q = 0; q < 4; ++q) {
                int w0 = m0 + (q << 3) + (lh << 2);
                bf16x4 v;
#pragma unroll
                for (int e = 0; e < 4; ++e) v[e] = (__bf16)(acc[q * 4 + e] + bias);
                *(bf16x4*)(lds + FPTo + swz(cg, w0 * 2)) = v;
            }
        }

        // ===== B2: f_g = xb @ w_g + b -> FGT ([c][w])
#pragma unroll
        for (int i = 0; i < 16; ++i) { accA[i] = 0.f; accB[i] = 0.f; }
#pragma unroll
        for (int j = 0; j < 8; ++j) {
            bf16x8 b0 = *(const bf16x8*)(pG + (((c0 * 8 + j) * 64 + l) << 3));
            bf16x8 b1 = *(const bf16x8*)(pG + (((c1 * 8 + j) * 64 + l) << 3));
            accA = __builtin_amdgcn_mfma_f32_32x32x16_bf16(xf[j], b0, accA, 0, 0, 0);
            accB = __builtin_amdgcn_mfma_f32_32x32x16_bf16(xf[j], b1, accB, 0, 0, 0);
            if (j & 1) __builtin_amdgcn_sched_barrier(0);
        }
#pragma unroll
        for (int t = 0; t < 2; ++t) {
            const f32x16& acc = t ? accB : accA;
            int cg = colg0 + t * 32;
            float bias = t ? biasG1 : biasG0;
#pragma unroll
            for (int q = 0; q < 4; ++q) {
                int w0 = m0 + (q << 3) + (lh << 2);
                bf16x4 v;
#pragma unroll
                for (int e = 0; e < 4; ++e) v[e] = (__bf16)(acc[q * 4 + e] + bias);
                *(bf16x4*)(lds + FGT + swz(cg, w0 * 2)) = v;
            }
        }
        bar();   // (1) FPB/FPT/FGT ready

        // issue chunk0 of next strip's x (rides across barriers; used after bar4)
        if (it + 1 < spb) {
            long base = (long)(s + 1) * 4096;
#pragma unroll
            for (int q = 0; q < 4; ++q) pf[q] = x4[base + q * 512 + tid];
        }

        // ===== D: v-logits  D[j][i] = sum_w fp[w][j] * fg[w][i]
#pragma unroll
        for (int i = 0; i < 16; ++i) { accA[i] = 0.f; accB[i] = 0.f; }
#pragma unroll 2
        for (int kk = 0; kk < 8; ++kk) {
            bf16x8 a  = *(const bf16x8*)(lds + FPTo + swz(m0 + ln, kk * 32 + lh * 16));
            bf16x8 b0 = *(const bf16x8*)(lds + FGT + swz(colg0, kk * 32 + lh * 16));
            bf16x8 b1 = *(const bf16x8*)(lds + FGT + swz(colg1, kk * 32 + lh * 16));
            accA = __builtin_amdgcn_mfma_f32_32x32x16_bf16(a, b0, accA, 0, 0, 0);
            accB = __builtin_amdgcn_mfma_f32_32x32x16_bf16(a, b1, accB, 0, 0, 0);
        }
        bar();   // (2) all D reads of FPT/FGT done

        // V epilogue: V[i][j] = sigm(D[j][i]) * x[i][j]  -> overwrite FGT
#pragma unroll
        for (int t = 0; t < 2; ++t) {
            const f32x16& acc = t ? accB : accA;
            int cg = colg0 + t * 32;
#pragma unroll
            for (int q = 0; q < 4; ++q) {
                int j0 = m0 + (q << 3) + (lh << 2);
                bf16x4 xv = *(const bf16x4*)(lds + XBo + swz(cg, j0 * 2));
                bf16x4 v;
#pragma unroll
                for (int e = 0; e < 4; ++e)
                    v[e] = (__bf16)(sigm(acc[q * 4 + e]) * (float)xv[e]);
                *(bf16x4*)(lds + FGT + swz(cg, j0 * 2)) = v;
            }
        }

        // ===== B3: f_theta = xb @ w_theta + b -> FPT slot (row-major "ftb")
#pragma unroll
        for (int i = 0; i < 16; ++i) { accA[i] = 0.f; accB[i] = 0.f; }
#pragma unroll
        for (int j = 0; j < 8; ++j) {
            bf16x8 b0 = *(const bf16x8*)(pTH + (((c0 * 8 + j) * 64 + l) << 3));
            bf16x8 b1 = *(const bf16x8*)(pTH + (((c1 * 8 + j) * 64 + l) << 3));
            accA = __builtin_amdgcn_mfma_f32_32x32x16_bf16(xf[j], b0, accA, 0, 0, 0);
            accB = __builtin_amdgcn_mfma_f32_32x32x16_bf16(xf[j], b1, accB, 0, 0, 0);
            if (j & 1) __builtin_amdgcn_sched_barrier(0);
        }
#pragma unroll
        for (int t = 0; t < 2; ++t) {
            const f32x16& acc = t ? accB : accA;
            int cg = colg0 + t * 32;
            float bias = t ? biasTH1 : biasTH0;
#pragma unroll
            for (int r = 0; r < 16; ++r) {
                int row = m0 + (r & 3) + ((r >> 2) << 3) + (lh << 2);
                *(__bf16*)(lds + FPTo + swz(row, cg * 2)) = (__bf16)(acc[r] + bias);
            }
        }
        bar();   // (3) V + ftb ready

        // ===== C: h-logits  D[v][w] = sum_c ft[v][c] * fp[w][c]
#pragma unroll
        for (int i = 0; i < 16; ++i) { accA[i] = 0.f; accB[i] = 0.f; }
#pragma unroll 2
        for (int kk = 0; kk < 8; ++kk) {
            bf16x8 a  = *(const bf16x8*)(lds + FPTo + swz(m0 + ln, kk * 32 + lh * 16));
            bf16x8 b0 = *(const bf16x8*)(lds + FPB + swz(colg0, kk * 32 + lh * 16));
            bf16x8 b1 = *(const bf16x8*)(lds + FPB + swz(colg1, kk * 32 + lh * 16));
            accA = __builtin_amdgcn_mfma_f32_32x32x16_bf16(a, b0, accA, 0, 0, 0);
            accB = __builtin_amdgcn_mfma_f32_32x32x16_bf16(a, b1, accB, 0, 0, 0);
        }
        bar();   // (4) all C reads of FPB/FPT done; FPT region now free

        // write chunk0 of next x into FPT region (= next iteration's XB)
        if (it + 1 < spb) {
#pragma unroll
            for (int q = 0; q < 4; ++q) {
                int row = q * 16 + srow;     // rows 0..63
                bf16x4 v;
                v[0] = (__bf16)pf[q].x; v[1] = (__bf16)pf[q].y;
                v[2] = (__bf16)pf[q].z; v[3] = (__bf16)pf[q].w;
                *(bf16x4*)(lds + FPTo + swz(row, scb)) = v;
            }
            // issue chunk1 loads (ride across bar5, used after E)
            long base = (long)(s + 1) * 4096;
#pragma unroll
            for (int q = 0; q < 4; ++q) pf[q] = x4[base + (4 + q) * 512 + tid];
        }

        // H epilogue: H[w][v] = sigm(D[v][w]) * x[w][v] -> overwrite FPB
#pragma unroll
        for (int t = 0; t < 2; ++t) {
            const f32x16& acc = t ? accB : accA;
            int cg = colg0 + t * 32;
#pragma unroll
            for (int q = 0; q < 4; ++q) {
                int v0 = m0 + (q << 3) + (lh << 2);
                bf16x4 xv = *(const bf16x4*)(lds + XBo + swz(cg, v0 * 2));
                bf16x4 v;
#pragma unroll
                for (int e = 0; e < 4; ++e)
                    v[e] = (__bf16)(sigm(acc[q * 4 + e]) * (float)xv[e]);
                *(bf16x4*)(lds + FPB + swz(cg, v0 * 2)) = v;
            }
        }
        bar();   // (5) H ready

        // ===== E: out = H @ Wo0 + V @ Wo2 + xb @ Wsc2 + bout2
#pragma unroll
        for (int i = 0; i < 16; ++i) { accA[i] = 0.f; accB[i] = 0.f; }
#pragma unroll 2
        for (int kk = 0; kk < 8; ++kk) {
            bf16x8 a  = *(const bf16x8*)(lds + FPB + swz(m0 + ln, kk * 32 + lh * 16));
            bf16x8 b0 = *(const bf16x8*)(pO0 + (((c0 * 8 + kk) * 64 + l) << 3));
            bf16x8 b1 = *(const bf16x8*)(pO0 + (((c1 * 8 + kk) * 64 + l) << 3));
            accA = __builtin_amdgcn_mfma_f32_32x32x16_bf16(a, b0, accA, 0, 0, 0);
            accB = __builtin_amdgcn_mfma_f32_32x32x16_bf16(a, b1, accB, 0, 0, 0);
        }
#pragma unroll 2
        for (int kk = 0; kk < 8; ++kk) {
            bf16x8 a  = *(const bf16x8*)(lds + FGT + swz(m0 + ln, kk * 32 + lh * 16));
            bf16x8 b0 = *(const bf16x8*)(pO2 + (((c0 * 8 + kk) * 64 + l) << 3));
            bf16x8 b1 = *(const bf16x8*)(pO2 + (((c1 * 8 + kk) * 64 + l) << 3));
            accA = __builtin_amdgcn_mfma_f32_32x32x16_bf16(a, b0, accA, 0, 0, 0);
            accB = __builtin_amdgcn_mfma_f32_32x32x16_bf16(a, b1, accB, 0, 0, 0);
        }
#pragma unroll
        for (int j = 0; j < 8; ++j) {
            bf16x8 b0 = *(const bf16x8*)(pS2 + (((c0 * 8 + j) * 64 + l) << 3));
            bf16x8 b1 = *(const bf16x8*)(pS2 + (((c1 * 8 + j) * 64 + l) << 3));
            accA = __builtin_amdgcn_mfma_f32_32x32x16_bf16(xf[j], b0, accA, 0, 0, 0);
            accB = __builtin_amdgcn_mfma_f32_32x32x16_bf16(xf[j], b1, accB, 0, 0, 0);
            if (j & 1) __builtin_amdgcn_sched_barrier(0);
        }
        {
            long obase = (long)s * 16384;
#pragma unroll
            for (int t = 0; t < 2; ++t) {
                const f32x16& acc = t ? accB : accA;
                int cg = colg0 + t * 32;
                float bias = t ? biasO1 : biasO0;
#pragma unroll
                for (int r = 0; r < 16; ++r) {
                    int row = m0 + (r & 3) + ((r >> 2) << 3) + (lh << 2);
                    out[obase + row * 128 + cg] = acc[r] + bias;
                }
            }
        }

        // write chunk1 of next x into FPT region (rows 64..127)
        if (it + 1 < spb) {
#pragma unroll
            for (int q = 0; q < 4; ++q) {
                int row = 64 + q * 16 + srow;
                bf16x4 v;
                v[0] = (__bf16)pf[q].x; v[1] = (__bf16)pf[q].y;
                v[2] = (__bf16)pf[q].z; v[3] = (__bf16)pf[q].w;
                *(bf16x4*)(lds + FPTo + swz(row, scb)) = v;
            }
        }
        bar();   // (6) E's LDS reads + next-x staging done
    }
}

extern "C" void kernel_launch(void* const* d_in, const int* in_sizes, int n_in,
                              void* d_out, int out_size, void* d_ws, size_t ws_size,
                              hipStream_t stream) {
    const float* x       = (const float*)d_in[0];
    const float* w_theta = (const float*)d_in[1];
    const float* b_theta = (const float*)d_in[2];
    const float* w_phi   = (const float*)d_in[3];
    const float* b_phi   = (const float*)d_in[4];
    const float* w_g     = (const float*)d_in[5];
    const float* b_g     = (const float*)d_in[6];
    const float* w_sc    = (const float*)d_in[7];
    const float* b_sc    = (const float*)d_in[8];
    const float* w_out   = (const float*)d_in[9];
    const float* b_out   = (const float*)d_in[10];
    float* out = (float*)d_out;

    float* wsc2 = (float*)d_ws;                                        // 128*128 f32
    __bf16* packs = (__bf16*)((char*)d_ws + 65536);                    // 6*16384 bf16
    float* bout2 = (float*)((char*)d_ws + 65536 + 6 * 16384 * 2);      // 128 f32

    int NS = in_sizes[0] / 16384;   // 2048 strips
    int spb = NS / 256;             // strips per block (8)
    if (spb < 1) spb = 1;
    int grid = (NS + spb - 1) / spb;

    prep_combine<<<128, 128, 0, stream>>>(w_sc, b_sc, w_out, b_out, wsc2, bout2);
    prep_pack<<<6, 256, 0, stream>>>(w_theta, w_phi, w_g, w_out, wsc2, packs);
    cab_main<<<grid, 512, 0, stream>>>(x, b_theta, b_phi, b_g, packs, bout2, out, NS, spb);
}

// Round 11
// 177.448 us; speedup vs baseline: 2.2068x; 2.2068x over previous
//
#include <hip/hip_runtime.h>

// ContextAttentionBlock fused kernel for gfx950.
// Per (b,h) row-strip (2048 strips of [128x128]): everything in LDS with
// bf16 MFMA (32x32x16), fp32 accum. Shortcut conv folded into the output
// projection (w_sc @ Wo1 precomputed).
//
// Notes (measured R1-R10):
//  - hipcc allocates VGPR = 65536/blockDim (512->128, 1024->64). Fit the cap.
//  - unroll 2 on kk loops is the spill sweet spot (R6); unroll 4 re-spills
//    (R7); xf-register-caching + dual acc at 512thr re-spills hard (R10).
//  - 1024 thr / 16 waves / one 32x32 tile per wave: ~60 VGPR live,
//    4 waves/SIMD (R8: 242->162us, occupancy 44%). Best known structure.
//  - R11: in-loop barriers are lgkmcnt-only (s_barrier), NOT __syncthreads
//    (which drains vmcnt(0) and kills the cross-barrier x-prefetch).
//  - LDS rotation: FPT region is dead after phase C, so next strip's x is
//    staged there; XB/FPT roles swap each iteration.

typedef __bf16 bf16x8 __attribute__((ext_vector_type(8)));
typedef __bf16 bf16x4 __attribute__((ext_vector_type(4)));
typedef float f32x16 __attribute__((ext_vector_type(16)));

// byte offset inside a [128][128] bf16 buffer (256 B rows).
// XOR of row bits into byte-offset bits 4..7 spreads 32-consecutive-row
// column accesses over 16 distinct 16B slots (R2: conflicts 13.1M -> 2.6M).
__device__ __forceinline__ int swz(int row, int cb) {
    return (row << 8) + (cb ^ ((row & 15) << 4));
}
__device__ __forceinline__ float sigm(float t) {
    return 1.0f / (1.0f + __expf(-t));
}
// lgkm-only barrier: each wave drains its OWN LDS ops (reads into regs,
// writes to LDS) then barriers -> LDS state consistent across the block,
// but in-flight GLOBAL prefetch loads (vmcnt) are NOT drained and ride
// through to their register use (compiler inserts the vmcnt wait there).
__device__ __forceinline__ void bar() {
    asm volatile("s_waitcnt lgkmcnt(0)" ::: "memory");
    __builtin_amdgcn_s_barrier();
    asm volatile("" ::: "memory");
}

// ---------------- pre-pass 1: combined shortcut weight -----------------
__global__ void prep_combine(const float* __restrict__ w_sc,
                             const float* __restrict__ b_sc,
                             const float* __restrict__ w_out,
                             const float* __restrict__ b_out,
                             float* __restrict__ wsc2,
                             float* __restrict__ bout2) {
    int k = blockIdx.x;      // 0..127
    int n = threadIdx.x;     // 0..127
    float acc = 0.f;
    for (int c = 0; c < 128; ++c)
        acc += w_sc[k * 128 + c] * w_out[(128 + c) * 128 + n];
    wsc2[k * 128 + n] = acc;
    if (k == 0) {
        float b = b_out[n];
        for (int c = 0; c < 128; ++c)
            b += b_sc[c] * w_out[(128 + c) * 128 + n];
        bout2[n] = b;
    }
}

// ---------------- pre-pass 2: pack weights into MFMA B-frag order ------
__global__ void prep_pack(const float* __restrict__ wth,
                          const float* __restrict__ wph,
                          const float* __restrict__ wg,
                          const float* __restrict__ wout,
                          const float* __restrict__ wsc2,
                          __bf16* __restrict__ packs) {
    int m = blockIdx.x;
    const float* src;
    int rowoff = 0;
    if (m == 0) src = wth;
    else if (m == 1) src = wph;
    else if (m == 2) src = wg;
    else if (m == 3) { src = wout; rowoff = 0; }
    else if (m == 4) { src = wout; rowoff = 256; }
    else src = wsc2;
    __bf16* dst = packs + m * 16384;
    for (int i = threadIdx.x; i < 16384; i += blockDim.x) {
        int j = i & 7;
        int lane = (i >> 3) & 63;
        int kk = (i >> 9) & 7;
        int nt = i >> 12;
        int k = kk * 16 + ((lane >> 5) << 3) + j;
        int n = nt * 32 + (lane & 31);
        dst[i] = (__bf16)(src[(rowoff + k) * 128 + n]);
    }
}

// ---------------- main fused kernel ------------------------------------
#define FPB 32768
#define FGT 98304

__global__ __launch_bounds__(1024, 1)
void cab_main(const float* __restrict__ x,
              const float* __restrict__ b_theta,
              const float* __restrict__ b_phi,
              const float* __restrict__ b_g,
              const __bf16* __restrict__ packs,
              const float* __restrict__ bout2,
              float* __restrict__ out,
              int nstrips, int spb) {
    __shared__ __align__(16) char lds[131072];

    const int tid = threadIdx.x;
    const int l   = tid & 63;
    const int wv  = tid >> 6;          // 0..15
    const int ct  = wv & 3;            // tile col (0..3)
    const int rt  = wv >> 2;           // tile row (0..3)
    const int ln  = l & 31;
    const int lh  = l >> 5;
    const int colg = ct * 32 + ln;     // this wave's output column
    const int m0   = rt * 32;          // this wave's output row base

    const __bf16* pTH = packs;
    const __bf16* pPH = packs + 16384;
    const __bf16* pG  = packs + 2 * 16384;
    const __bf16* pO0 = packs + 3 * 16384;
    const __bf16* pO2 = packs + 4 * 16384;
    const __bf16* pS2 = packs + 5 * 16384;

    const float biasTH = b_theta[colg];
    const float biasPH = b_phi[colg];
    const float biasG  = b_g[colg];
    const float biasO  = bout2[colg];

    const int s0 = blockIdx.x * spb;
    if (s0 >= nstrips) return;
    const float4* x4 = (const float4*)x;

    // staging geometry (1024 thr): idx = q*1024+tid -> row = q*32 + (tid>>5),
    // byte col = (tid&31)*8. Chunk c covers q = {2c, 2c+1} (rows c*64..c*64+63).
    const int srow = tid >> 5;          // 0..31
    const int scb  = (tid & 31) * 8;    // byte col

    float4 pf[2];

    // initial full stage of strip s0 into region 0
    {
        long base = (long)s0 * 4096;
#pragma unroll
        for (int c = 0; c < 2; ++c) {
#pragma unroll
            for (int q = 0; q < 2; ++q) pf[q] = x4[base + (c * 2 + q) * 1024 + tid];
#pragma unroll
            for (int q = 0; q < 2; ++q) {
                int row = (c * 2 + q) * 32 + srow;
                bf16x4 v;
                v[0] = (__bf16)pf[q].x; v[1] = (__bf16)pf[q].y;
                v[2] = (__bf16)pf[q].z; v[3] = (__bf16)pf[q].w;
                *(bf16x4*)(lds + swz(row, scb)) = v;
            }
        }
    }
    bar();

    for (int it = 0; it < spb; ++it) {
        const int s = s0 + it;
        // rotating roles: XB holds current x; FPT region doubles as next-XB
        const int XBo  = (it & 1) ? 65536 : 0;
        const int FPTo = 65536 - XBo;
        f32x16 acc;

        // ===== B1: f_phi = xb @ w_phi + b  -> FPB (row-major) + FPT ([c][w])
#pragma unroll
        for (int i = 0; i < 16; ++i) acc[i] = 0.f;
#pragma unroll 2
        for (int kk = 0; kk < 8; ++kk) {
            bf16x8 b = *(const bf16x8*)(pPH + (((ct * 8 + kk) * 64 + l) << 3));
            bf16x8 a = *(const bf16x8*)(lds + XBo + swz(m0 + ln, kk * 32 + lh * 16));
            acc = __builtin_amdgcn_mfma_f32_32x32x16_bf16(a, b, acc, 0, 0, 0);
        }
#pragma unroll
        for (int r = 0; r < 16; ++r) {
            int row = m0 + (r & 3) + ((r >> 2) << 3) + (lh << 2);
            *(__bf16*)(lds + FPB + swz(row, colg * 2)) = (__bf16)(acc[r] + biasPH);
        }
#pragma unroll
        for (int q = 0; q < 4; ++q) {
            int w0 = m0 + (q << 3) + (lh << 2);
            bf16x4 v;
#pragma unroll
            for (int e = 0; e < 4; ++e) v[e] = (__bf16)(acc[q * 4 + e] + biasPH);
            *(bf16x4*)(lds + FPTo + swz(colg, w0 * 2)) = v;
        }

        // ===== B2: f_g = xb @ w_g + b -> FGT ([c][w])
#pragma unroll
        for (int i = 0; i < 16; ++i) acc[i] = 0.f;
#pragma unroll 2
        for (int kk = 0; kk < 8; ++kk) {
            bf16x8 b = *(const bf16x8*)(pG + (((ct * 8 + kk) * 64 + l) << 3));
            bf16x8 a = *(const bf16x8*)(lds + XBo + swz(m0 + ln, kk * 32 + lh * 16));
            acc = __builtin_amdgcn_mfma_f32_32x32x16_bf16(a, b, acc, 0, 0, 0);
        }
#pragma unroll
        for (int q = 0; q < 4; ++q) {
            int w0 = m0 + (q << 3) + (lh << 2);
            bf16x4 v;
#pragma unroll
            for (int e = 0; e < 4; ++e) v[e] = (__bf16)(acc[q * 4 + e] + biasG);
            *(bf16x4*)(lds + FGT + swz(colg, w0 * 2)) = v;
        }
        bar();   // (1) FPB/FPT/FGT ready

        // issue chunk0 of next strip's x; with lgkm-only barriers these
        // loads stay in flight until the ds_write after bar(4)
        if (it + 1 < spb) {
            long base = (long)(s + 1) * 4096;
#pragma unroll
            for (int q = 0; q < 2; ++q) pf[q] = x4[base + q * 1024 + tid];
        }

        // ===== D: v-logits  D[j][i] = sum_w fp[w][j] * fg[w][i]
#pragma unroll
        for (int i = 0; i < 16; ++i) acc[i] = 0.f;
#pragma unroll 2
        for (int kk = 0; kk < 8; ++kk) {
            bf16x8 b = *(const bf16x8*)(lds + FGT + swz(colg, kk * 32 + lh * 16));
            bf16x8 a = *(const bf16x8*)(lds + FPTo + swz(m0 + ln, kk * 32 + lh * 16));
            acc = __builtin_amdgcn_mfma_f32_32x32x16_bf16(a, b, acc, 0, 0, 0);
        }
        bar();   // (2) all D reads of FPT/FGT done

        // V epilogue: V[i][j] = sigm(D[j][i]) * x[i][j]  -> overwrite FGT
#pragma unroll
        for (int q = 0; q < 4; ++q) {
            int j0 = m0 + (q << 3) + (lh << 2);
            bf16x4 xv = *(const bf16x4*)(lds + XBo + swz(colg, j0 * 2));
            bf16x4 v;
#pragma unroll
            for (int e = 0; e < 4; ++e)
                v[e] = (__bf16)(sigm(acc[q * 4 + e]) * (float)xv[e]);
            *(bf16x4*)(lds + FGT + swz(colg, j0 * 2)) = v;
        }

        // ===== B3: f_theta = xb @ w_theta + b -> FPT slot (row-major "ftb")
#pragma unroll
        for (int i = 0; i < 16; ++i) acc[i] = 0.f;
#pragma unroll 2
        for (int kk = 0; kk < 8; ++kk) {
            bf16x8 b = *(const bf16x8*)(pTH + (((ct * 8 + kk) * 64 + l) << 3));
            bf16x8 a = *(const bf16x8*)(lds + XBo + swz(m0 + ln, kk * 32 + lh * 16));
            acc = __builtin_amdgcn_mfma_f32_32x32x16_bf16(a, b, acc, 0, 0, 0);
        }
#pragma unroll
        for (int r = 0; r < 16; ++r) {
            int row = m0 + (r & 3) + ((r >> 2) << 3) + (lh << 2);
            *(__bf16*)(lds + FPTo + swz(row, colg * 2)) = (__bf16)(acc[r] + biasTH);
        }
        bar();   // (3) V + ftb ready

        // ===== C: h-logits  D[v][w] = sum_c ft[v][c] * fp[w][c]
#pragma unroll
        for (int i = 0; i < 16; ++i) acc[i] = 0.f;
#pragma unroll 2
        for (int kk = 0; kk < 8; ++kk) {
            bf16x8 b = *(const bf16x8*)(lds + FPB + swz(colg, kk * 32 + lh * 16));
            bf16x8 a = *(const bf16x8*)(lds + FPTo + swz(m0 + ln, kk * 32 + lh * 16));
            acc = __builtin_amdgcn_mfma_f32_32x32x16_bf16(a, b, acc, 0, 0, 0);
        }
        bar();   // (4) all C reads of FPB/FPT done; FPT region now free

        // write chunk0 of next x into FPT region (= next iteration's XB)
        if (it + 1 < spb) {
#pragma unroll
            for (int q = 0; q < 2; ++q) {
                int row = q * 32 + srow;     // rows 0..63
                bf16x4 v;
                v[0] = (__bf16)pf[q].x; v[1] = (__bf16)pf[q].y;
                v[2] = (__bf16)pf[q].z; v[3] = (__bf16)pf[q].w;
                *(bf16x4*)(lds + FPTo + swz(row, scb)) = v;
            }
            // issue chunk1 loads (ride across bar(5) to the write after E)
            long base = (long)(s + 1) * 4096;
#pragma unroll
            for (int q = 0; q < 2; ++q) pf[q] = x4[base + (2 + q) * 1024 + tid];
        }

        // H epilogue: H[w][v] = sigm(D[v][w]) * x[w][v] -> overwrite FPB
#pragma unroll
        for (int q = 0; q < 4; ++q) {
            int v0 = m0 + (q << 3) + (lh << 2);
            bf16x4 xv = *(const bf16x4*)(lds + XBo + swz(colg, v0 * 2));
            bf16x4 v;
#pragma unroll
            for (int e = 0; e < 4; ++e)
                v[e] = (__bf16)(sigm(acc[q * 4 + e]) * (float)xv[e]);
            *(bf16x4*)(lds + FPB + swz(colg, v0 * 2)) = v;
        }
        bar();   // (5) H ready

        // ===== E: out = H @ Wo0 + V @ Wo2 + xb @ Wsc2 + bout2
#pragma unroll
        for (int i = 0; i < 16; ++i) acc[i] = 0.f;
#pragma unroll 2
        for (int kk = 0; kk < 8; ++kk) {
            bf16x8 b = *(const bf16x8*)(pO0 + (((ct * 8 + kk) * 64 + l) << 3));
            bf16x8 a = *(const bf16x8*)(lds + FPB + swz(m0 + ln, kk * 32 + lh * 16));
            acc = __builtin_amdgcn_mfma_f32_32x32x16_bf16(a, b, acc, 0, 0, 0);
        }
#pragma unroll 2
        for (int kk = 0; kk < 8; ++kk) {
            bf16x8 b = *(const bf16x8*)(pO2 + (((ct * 8 + kk) * 64 + l) << 3));
            bf16x8 a = *(const bf16x8*)(lds + FGT + swz(m0 + ln, kk * 32 + lh * 16));
            acc = __builtin_amdgcn_mfma_f32_32x32x16_bf16(a, b, acc, 0, 0, 0);
        }
#pragma unroll 2
        for (int kk = 0; kk < 8; ++kk) {
            bf16x8 b = *(const bf16x8*)(pS2 + (((ct * 8 + kk) * 64 + l) << 3));
            bf16x8 a = *(const bf16x8*)(lds + XBo + swz(m0 + ln, kk * 32 + lh * 16));
            acc = __builtin_amdgcn_mfma_f32_32x32x16_bf16(a, b, acc, 0, 0, 0);
        }
        {
            long obase = (long)s * 16384;
#pragma unroll
            for (int r = 0; r < 16; ++r) {
                int row = m0 + (r & 3) + ((r >> 2) << 3) + (lh << 2);
                out[obase + row * 128 + colg] = acc[r] + biasO;
            }
        }

        // write chunk1 of next x into FPT region (rows 64..127)
        if (it + 1 < spb) {
#pragma unroll
            for (int q = 0; q < 2; ++q) {
                int row = 64 + q * 32 + srow;
                bf16x4 v;
                v[0] = (__bf16)pf[q].x; v[1] = (__bf16)pf[q].y;
                v[2] = (__bf16)pf[q].z; v[3] = (__bf16)pf[q].w;
                *(bf16x4*)(lds + FPTo + swz(row, scb)) = v;
            }
        }
        bar();   // (6) E's XB reads + next-x staging done
    }
}

extern "C" void kernel_launch(void* const* d_in, const int* in_sizes, int n_in,
                              void* d_out, int out_size, void* d_ws, size_t ws_size,
                              hipStream_t stream) {
    const float* x       = (const float*)d_in[0];
    const float* w_theta = (const float*)d_in[1];
    const float* b_theta = (const float*)d_in[2];
    const float* w_phi   = (const float*)d_in[3];
    const float* b_phi   = (const float*)d_in[4];
    const float* w_g     = (const float*)d_in[5];
    const float* b_g     = (const float*)d_in[6];
    const float* w_sc    = (const float*)d_in[7];
    const float* b_sc    = (const float*)d_in[8];
    const float* w_out   = (const float*)d_in[9];
    const float* b_out   = (const float*)d_in[10];
    float* out = (float*)d_out;

    float* wsc2 = (float*)d_ws;                                        // 128*128 f32
    __bf16* packs = (__bf16*)((char*)d_ws + 65536);                    // 6*16384 bf16
    float* bout2 = (float*)((char*)d_ws + 65536 + 6 * 16384 * 2);      // 128 f32

    int NS = in_sizes[0] / 16384;   // 2048 strips
    int spb = NS / 256;             // strips per block (8)
    if (spb < 1) spb = 1;
    int grid = (NS + spb - 1) / spb;

    prep_combine<<<128, 128, 0, stream>>>(w_sc, b_sc, w_out, b_out, wsc2, bout2);
    prep_pack<<<6, 256, 0, stream>>>(w_theta, w_phi, w_g, w_out, wsc2, packs);
    cab_main<<<grid, 1024, 0, stream>>>(x, b_theta, b_phi, b_g, packs, bout2, out, NS, spb);
}